// Round 5
// baseline (2493.212 us; speedup 1.0000x reference)
//
#include <hip/hip_runtime.h>
#include <hip/hip_bf16.h>
#include <math.h>

#define BB 8
#define NN 4096
#define NIN 64
#define NOUTF 128
#define KNB 32
#define MM 1024
#define DIM 68
#define CAP 320

typedef float f32x2 __attribute__((ext_vector_type(2)));

__device__ __forceinline__ f32x2 pkmax(f32x2 a, f32x2 b)
{
    f32x2 r; r.x = fmaxf(a.x, b.x); r.y = fmaxf(a.y, b.y); return r;
}

// DPP max-reduce step: v = max(v, lanes-moved-v). CTRL compile-time.
template <int CTRL>
__device__ __forceinline__ float dppmax(float v)
{
    int m = __builtin_amdgcn_update_dpp(__float_as_int(v), __float_as_int(v),
                                        CTRL, 0xF, 0xF, false);
    return fmaxf(v, __int_as_float(m));
}

// ---------------------------------------------------------------------------
// Kernel 1: farthest point sampling. ONE WAVE per batch, serial over M steps.
// No __syncthreads, no cross-wave merge: wave argmax via DPP + ballot;
// winner coords via one broadcast ds_read_b128 from an LDS pos copy.
// Exact-match constraints: no FMA contraction, (dx*dx+dy*dy)+dz*dz order,
// argmax = first occurrence (max value, then min global index).
// Mapping p = lane*64 + k: lane order == global index order.
// ---------------------------------------------------------------------------
__global__ __launch_bounds__(64, 1) void fps_kernel(
    const float* __restrict__ pos,
    int* __restrict__ idx_ws, float* __restrict__ pos_s_ws,
    float* __restrict__ out_pos_s, float* __restrict__ out_idx)
{
#pragma clang fp contract(off)
    __shared__ float4 posL[NN];   // 64 KiB: coords for winner broadcast

    const int b    = blockIdx.x;
    const int lane = threadIdx.x;   // 0..63, one wave
    const float* pb = pos + (size_t)b * NN * 3;

    // 64 consecutive points per lane: p = lane*64 + k.
    // Packed pairs: X[j].x <-> k=2j, X[j].y <-> k=2j+1.  (4*64 = 256 VGPRs)
    f32x2 X[32], Y[32], Z[32], D[32];
#pragma unroll
    for (int j = 0; j < 32; ++j) {
        int pA = lane * 64 + 2 * j;
        float x0 = pb[pA * 3 + 0], y0 = pb[pA * 3 + 1], z0 = pb[pA * 3 + 2];
        float x1 = pb[pA * 3 + 3], y1 = pb[pA * 3 + 4], z1 = pb[pA * 3 + 5];
        X[j].x = x0; X[j].y = x1;
        Y[j].x = y0; Y[j].y = y1;
        Z[j].x = z0; Z[j].y = z1;
        D[j].x = INFINITY; D[j].y = INFINITY;
        posL[pA]     = make_float4(x0, y0, z0, 0.0f);
        posL[pA + 1] = make_float4(x1, y1, z1, 0.0f);
    }
    // single wave: LDS write->read ordering handled by compiler waitcnts

    int   last = 0;
    float lx = pb[0], ly = pb[1], lz = pb[2];

    for (int t = 0; t < MM; ++t) {
        // emit current sample (off critical path: stores feed nothing)
        if (lane == 0) {
            idx_ws[b * MM + t]  = last;
            out_idx[b * MM + t] = (float)last;
            pos_s_ws[(b * MM + t) * 3 + 0] = lx;
            pos_s_ws[(b * MM + t) * 3 + 1] = ly;
            pos_s_ws[(b * MM + t) * 3 + 2] = lz;
            out_pos_s[(b * MM + t) * 3 + 0] = lx;
            out_pos_s[(b * MM + t) * 3 + 1] = ly;
            out_pos_s[(b * MM + t) * 3 + 2] = lz;
        }

        f32x2 lx2; lx2.x = lx; lx2.y = lx;
        f32x2 ly2; ly2.x = ly; ly2.y = ly;
        f32x2 lz2; lz2.x = lz; lz2.y = lz;

        // min-update scan (no argmax tracking), contract off => exact
#pragma unroll
        for (int j = 0; j < 32; ++j) {
            f32x2 dx = X[j] - lx2;
            f32x2 dy = Y[j] - ly2;
            f32x2 dz = Z[j] - lz2;
            f32x2 s  = (dx * dx + dy * dy) + dz * dz;
            D[j].x = fminf(D[j].x, s.x);
            D[j].y = fminf(D[j].y, s.y);
        }

        // lane max via pkmax tree
        f32x2 a0  = pkmax(D[0], D[1]),   a1  = pkmax(D[2], D[3]);
        f32x2 a2  = pkmax(D[4], D[5]),   a3  = pkmax(D[6], D[7]);
        f32x2 a4  = pkmax(D[8], D[9]),   a5  = pkmax(D[10], D[11]);
        f32x2 a6  = pkmax(D[12], D[13]), a7  = pkmax(D[14], D[15]);
        f32x2 a8  = pkmax(D[16], D[17]), a9  = pkmax(D[18], D[19]);
        f32x2 a10 = pkmax(D[20], D[21]), a11 = pkmax(D[22], D[23]);
        f32x2 a12 = pkmax(D[24], D[25]), a13 = pkmax(D[26], D[27]);
        f32x2 a14 = pkmax(D[28], D[29]), a15 = pkmax(D[30], D[31]);
        a0 = pkmax(a0, a8);  a1 = pkmax(a1, a9);
        a2 = pkmax(a2, a10); a3 = pkmax(a3, a11);
        a4 = pkmax(a4, a12); a5 = pkmax(a5, a13);
        a6 = pkmax(a6, a14); a7 = pkmax(a7, a15);
        a0 = pkmax(a0, a4); a1 = pkmax(a1, a5);
        a2 = pkmax(a2, a6); a3 = pkmax(a3, a7);
        a0 = pkmax(a0, a2); a1 = pkmax(a1, a3);
        a0 = pkmax(a0, a1);
        float bv = fmaxf(a0.x, a0.y);

        // per-lane first-argmax recovery: independent leaves + min tree
        // (issues in parallel with the DPP chain below; all inline consts)
        int km[32];
#pragma unroll
        for (int j = 0; j < 32; ++j) {
            km[j] = (D[j].x == bv) ? (2 * j) : ((D[j].y == bv) ? (2 * j + 1) : 64);
        }
#pragma unroll
        for (int s2 = 16; s2 >= 1; s2 >>= 1)
#pragma unroll
            for (int j = 0; j < s2; ++j) km[j] = min(km[j], km[j + s2]);
        int p_cand = lane * 64 + km[0];

        // VALU-speed wave max-reduce: row_shr 1/2/4/8, row_bcast 15/31
        float r = bv;
        r = dppmax<0x111>(r);
        r = dppmax<0x112>(r);
        r = dppmax<0x114>(r);
        r = dppmax<0x118>(r);
        r = dppmax<0x142>(r);
        r = dppmax<0x143>(r);
        float wmax = __int_as_float(__builtin_amdgcn_readlane(__float_as_int(r), 63));

        // winner = lowest lane matching wmax (== smallest global index)
        unsigned long long msk = __ballot(bv == wmax);
        int wl = __ffsll((long long)msk) - 1;

        int pwin = __builtin_amdgcn_readlane(p_cand, wl);
        float4 cw = posL[pwin];        // broadcast read, no conflict
        last = pwin; lx = cw.x; ly = cw.y; lz = cw.z;
    }
}

// ---------------------------------------------------------------------------
// Kernel 2: radius search + exact K-smallest selection. One wave per center.
// ---------------------------------------------------------------------------
__global__ __launch_bounds__(256) void radius_kernel(
    const float* __restrict__ pos,
    const float* __restrict__ pos_s_ws,
    int* __restrict__ nbr_ws, int* __restrict__ nvalid_ws)
{
    __shared__ float d2L[4][CAP];
    __shared__ int   idL[4][CAP];
    __shared__ int   cntL[4];

    const int wv = threadIdx.x >> 6, lane = threadIdx.x & 63;
    const int c = blockIdx.x * 4 + wv;
    const int b = c >> 10;
    const float RSQ = 0.0225f;

    if (lane == 0) cntL[wv] = 0;

    float cx = pos_s_ws[c * 3 + 0];
    float cy = pos_s_ws[c * 3 + 1];
    float cz = pos_s_ws[c * 3 + 2];
    const float* pb = pos + (size_t)b * NN * 3;

    for (int it = 0; it < NN / 64; ++it) {
        int p = it * 64 + lane;
        float dx = __fsub_rn(cx, pb[p * 3 + 0]);
        float dy = __fsub_rn(cy, pb[p * 3 + 1]);
        float dz = __fsub_rn(cz, pb[p * 3 + 2]);
        float d2 = __fadd_rn(__fadd_rn(__fmul_rn(dx, dx), __fmul_rn(dy, dy)),
                             __fmul_rn(dz, dz));
        if (d2 <= RSQ) {
            int slot = atomicAdd(&cntL[wv], 1);
            if (slot < CAP) { d2L[wv][slot] = d2; idL[wv][slot] = p; }
        }
    }
    int n = cntL[wv];
    if (n > CAP) n = CAP;

    if (n <= KNB) {
        if (lane == 0) nvalid_ws[c] = n;
        if (lane < n) nbr_ws[c * KNB + lane] = idL[wv][lane];
    } else {
        if (lane == 0) nvalid_ws[c] = KNB;
        for (int a = lane; a < n; a += 64) {
            float da = d2L[wv][a]; int ia = idL[wv][a];
            int r = 0;
            for (int jj = 0; jj < n; ++jj) {
                float dj = d2L[wv][jj]; int ij = idL[wv][jj];
                r += (dj < da || (dj == da && ij < ia)) ? 1 : 0;
            }
            if (r < KNB) nbr_ws[c * KNB + r] = ia;
        }
    }
}

// ---------------------------------------------------------------------------
// Kernel 3: message build (x_j ++ ppf) -> 68x68 MLP x2 -> masked max-agg ->
// 68x128 output matvec. Block = 2 centers (64 edges), weights in LDS.
// ---------------------------------------------------------------------------
__device__ __forceinline__ float angle3(float ax, float ay, float az,
                                        float bx, float by, float bz)
{
    float cx = ay * bz - az * by;
    float cy = az * bx - ax * bz;
    float cz = ax * by - ay * bx;
    float cn = sqrtf(cx * cx + cy * cy + cz * cz);
    float dt = ax * bx + ay * by + az * bz;
    return atan2f(cn, dt);
}

__device__ __forceinline__ void layer_pass(const float* __restrict__ inL,
                                           const float* __restrict__ Ws,
                                           const float* __restrict__ bs,
                                           float* __restrict__ outL, int t)
{
    const int e = t & 63, wvi = t >> 6;
    for (int jg = wvi; jg < 17; jg += 4) {
        float ax = bs[jg * 4 + 0];
        float ay = bs[jg * 4 + 1];
        float az = bs[jg * 4 + 2];
        float aw = bs[jg * 4 + 3];
#pragma unroll 4
        for (int i = 0; i < DIM; ++i) {
            float m = inL[e * 69 + i];
            const float4 w = *reinterpret_cast<const float4*>(Ws + i * DIM + jg * 4);
            ax = fmaf(m, w.x, ax);
            ay = fmaf(m, w.y, ay);
            az = fmaf(m, w.z, az);
            aw = fmaf(m, w.w, aw);
        }
        outL[e * 69 + jg * 4 + 0] = fmaxf(ax, 0.0f);
        outL[e * 69 + jg * 4 + 1] = fmaxf(ay, 0.0f);
        outL[e * 69 + jg * 4 + 2] = fmaxf(az, 0.0f);
        outL[e * 69 + jg * 4 + 3] = fmaxf(aw, 0.0f);
    }
}

__global__ __launch_bounds__(256) void mlp_kernel(
    const float* __restrict__ x, const float* __restrict__ pos,
    const float* __restrict__ norm,
    const float* __restrict__ W1, const float* __restrict__ b1,
    const float* __restrict__ W2, const float* __restrict__ b2,
    const float* __restrict__ W3, const float* __restrict__ b3,
    const int* __restrict__ idx_ws, const float* __restrict__ pos_s_ws,
    const int* __restrict__ nbr_ws, const int* __restrict__ nvalid_ws,
    float* __restrict__ out)
{
    __shared__ alignas(16) float W1s[DIM * DIM];
    __shared__ alignas(16) float W2s[DIM * DIM];
    __shared__ float b1s[DIM], b2s[DIM];
    __shared__ float msgL[64 * 69];   // msg, later reused as h2
    __shared__ float h1L[64 * 69];
    __shared__ float aggL[2 * DIM];
    __shared__ int   nvL[2], jLs[64];

    const int t = threadIdx.x;
    const int cg0 = blockIdx.x * 2;

    for (int u = t; u < DIM * DIM; u += 256) { W1s[u] = W1[u]; W2s[u] = W2[u]; }
    if (t < DIM) { b1s[t] = b1[t]; b2s[t] = b2[t]; }
    if (t < 2) nvL[t] = min(nvalid_ws[cg0 + t], KNB);
    __syncthreads();

    const int e = t & 63, fc = t >> 6;
    const int lc = e >> 5, slot = e & 31;
    const int c = cg0 + lc;
    const int b = c >> 10;

    if (fc == 0) {
        int nv = nvL[lc];
        jLs[e] = (slot < nv) ? nbr_ws[c * KNB + slot] : 0;
    }
    __syncthreads();

    const int j = jLs[e];
    // gather x_j (each thread: 16 features of its edge)
    {
        const float* xj = x + ((size_t)b * NN + j) * NIN + fc * 16;
#pragma unroll
        for (int r = 0; r < 4; ++r) {
            float4 v = *reinterpret_cast<const float4*>(xj + r * 4);
            msgL[e * 69 + fc * 16 + r * 4 + 0] = v.x;
            msgL[e * 69 + fc * 16 + r * 4 + 1] = v.y;
            msgL[e * 69 + fc * 16 + r * 4 + 2] = v.z;
            msgL[e * 69 + fc * 16 + r * 4 + 3] = v.w;
        }
    }
    // point-pair features (one thread per edge)
    if (fc == 0) {
        float pix = pos_s_ws[c * 3 + 0];
        float piy = pos_s_ws[c * 3 + 1];
        float piz = pos_s_ws[c * 3 + 2];
        int ic = idx_ws[c];
        const float* pj_ = pos  + ((size_t)b * NN + j) * 3;
        const float* nj_ = norm + ((size_t)b * NN + j) * 3;
        const float* ni_ = norm + ((size_t)b * NN + ic) * 3;
        float dx = pj_[0] - pix, dy = pj_[1] - piy, dz = pj_[2] - piz;
        float nix = ni_[0], niy = ni_[1], niz = ni_[2];
        float njx = nj_[0], njy = nj_[1], njz = nj_[2];
        msgL[e * 69 + 64] = sqrtf(dx * dx + dy * dy + dz * dz);
        msgL[e * 69 + 65] = angle3(nix, niy, niz, dx, dy, dz);
        msgL[e * 69 + 66] = angle3(njx, njy, njz, dx, dy, dz);
        msgL[e * 69 + 67] = angle3(nix, niy, niz, njx, njy, njz);
    }
    __syncthreads();

    layer_pass(msgL, W1s, b1s, h1L, t);
    __syncthreads();
    layer_pass(h1L, W2s, b2s, msgL, t);   // h2 -> msgL
    __syncthreads();

    // masked max aggregation over valid slots
    if (t < 2 * DIM) {
        int cc = t / DIM, jf = t % DIM;
        int nv = nvL[cc];
        float v = -INFINITY;
        for (int s = 0; s < nv; ++s)
            v = fmaxf(v, msgL[(cc * 32 + s) * 69 + jf]);
        aggL[cc * DIM + jf] = v;
    }
    __syncthreads();

    // out = relu(agg @ W3 + b3)
    {
        int cc = t >> 7, o = t & 127;
        int cgl = cg0 + cc;
        float acc = b3[o];
#pragma unroll 4
        for (int i = 0; i < DIM; ++i)
            acc = fmaf(aggL[cc * DIM + i], W3[i * NOUTF + o], acc);
        out[(size_t)cgl * NOUTF + o] = fmaxf(acc, 0.0f);
    }
}

// ---------------------------------------------------------------------------
extern "C" void kernel_launch(void* const* d_in, const int* in_sizes, int n_in,
                              void* d_out, int out_size, void* d_ws, size_t ws_size,
                              hipStream_t stream)
{
    const float* x    = (const float*)d_in[0];
    const float* pos  = (const float*)d_in[1];
    const float* norm = (const float*)d_in[2];
    // d_in[3] = batch (unused, implicit in layout)
    const float* W1 = (const float*)d_in[4];
    const float* b1 = (const float*)d_in[5];
    const float* W2 = (const float*)d_in[6];
    const float* b2 = (const float*)d_in[7];
    const float* W3 = (const float*)d_in[8];
    const float* b3 = (const float*)d_in[9];

    float* out       = (float*)d_out;                       // [B*M*128]
    float* out_pos_s = out + (size_t)BB * MM * NOUTF;       // [B*M*3]
    float* out_idx   = out_pos_s + (size_t)BB * MM * 3;     // [B*M]

    char* ws = (char*)d_ws;
    int*   idx_ws    = (int*)ws;                                    // B*M
    float* pos_s_ws  = (float*)(ws + 32768);                        // B*M*3
    int*   nbr_ws    = (int*)(ws + 131072);                         // B*M*K
    int*   nvalid_ws = (int*)(ws + 131072 + (size_t)BB * MM * KNB * 4);

    fps_kernel<<<dim3(BB), dim3(64), 0, stream>>>(pos, idx_ws, pos_s_ws,
                                                  out_pos_s, out_idx);
    radius_kernel<<<dim3((BB * MM) / 4), dim3(256), 0, stream>>>(pos, pos_s_ws,
                                                                 nbr_ws, nvalid_ws);
    mlp_kernel<<<dim3((BB * MM) / 2), dim3(256), 0, stream>>>(
        x, pos, norm, W1, b1, W2, b2, W3, b3,
        idx_ws, pos_s_ws, nbr_ws, nvalid_ws, out);
}

// Round 6
// 1064.992 us; speedup vs baseline: 2.3411x; 2.3411x over previous
//
#include <hip/hip_runtime.h>
#include <hip/hip_bf16.h>
#include <math.h>

#define BB 8
#define NN 4096
#define NIN 64
#define NOUTF 128
#define KNB 32
#define MM 1024
#define DIM 68
#define CAP 320

typedef float f32x2 __attribute__((ext_vector_type(2)));

__device__ __forceinline__ f32x2 pkmax(f32x2 a, f32x2 b)
{
    f32x2 r; r.x = fmaxf(a.x, b.x); r.y = fmaxf(a.y, b.y); return r;
}

// DPP max-reduce step: v = max(v, lanes-moved-v). CTRL compile-time.
template <int CTRL>
__device__ __forceinline__ float dppmax(float v)
{
    int m = __builtin_amdgcn_update_dpp(__float_as_int(v), __float_as_int(v),
                                        CTRL, 0xF, 0xF, false);
    return fmaxf(v, __int_as_float(m));
}

// ---------------------------------------------------------------------------
// Kernel 1: farthest point sampling. One block (4 waves) per batch.
// Exact-match constraints: no FMA contraction, (dx*dx+dy*dy)+dz*dz order,
// argmax = first occurrence (max value, then min global index).
// Thread-major mapping p = tid*16 + k: lane/wave order == index order.
// Hot loop: max-only scan -> DPP wave max -> ballot first-lane -> equality
// recovery of local k -> per-wave uniform slot -> 1 barrier -> 3-select
// merge -> winner coords via ONE broadcast ds_read_b128 from posL.
// ---------------------------------------------------------------------------
__global__ __launch_bounds__(256) void fps_kernel(
    const float* __restrict__ pos,
    int* __restrict__ idx_ws, float* __restrict__ pos_s_ws,
    float* __restrict__ out_pos_s, float* __restrict__ out_idx)
{
#pragma clang fp contract(off)
    __shared__ float4 posL[NN];        // 64 KiB coords for winner broadcast
    __shared__ f32x2  slot[2][4];      // {val, idx-as-float} per wave, dbuf

    const int b    = blockIdx.x;
    const int tid  = threadIdx.x;
    const int wv   = tid >> 6;
    const int lane = tid & 63;
    const float* pb = pos + (size_t)b * NN * 3;

    // 16 consecutive points per thread: p = tid*16 + k.
    // Packed pairs: X[j].x <-> k=2j, X[j].y <-> k=2j+1.
    f32x2 X[8], Y[8], Z[8], D[8];
#pragma unroll
    for (int j = 0; j < 8; ++j) {
        int pA = tid * 16 + 2 * j;
        X[j].x = pb[pA * 3 + 0]; X[j].y = pb[pA * 3 + 3];
        Y[j].x = pb[pA * 3 + 1]; Y[j].y = pb[pA * 3 + 4];
        Z[j].x = pb[pA * 3 + 2]; Z[j].y = pb[pA * 3 + 5];
        D[j].x = INFINITY;       D[j].y = INFINITY;
    }
    // coalesced posL init: consecutive threads -> consecutive float4
#pragma unroll
    for (int j = 0; j < 16; ++j) {
        int p2 = tid + 256 * j;
        posL[p2] = make_float4(pb[p2 * 3 + 0], pb[p2 * 3 + 1],
                               pb[p2 * 3 + 2], 0.0f);
    }
    __syncthreads();

    int   last = 0;
    float lx = pb[0], ly = pb[1], lz = pb[2];

    for (int t = 0; t < MM; ++t) {
        // emit current sample (stores feed nothing; off critical path)
        if (tid == 0) {
            idx_ws[b * MM + t]  = last;
            out_idx[b * MM + t] = (float)last;
            pos_s_ws[(b * MM + t) * 3 + 0] = lx;
            pos_s_ws[(b * MM + t) * 3 + 1] = ly;
            pos_s_ws[(b * MM + t) * 3 + 2] = lz;
            out_pos_s[(b * MM + t) * 3 + 0] = lx;
            out_pos_s[(b * MM + t) * 3 + 1] = ly;
            out_pos_s[(b * MM + t) * 3 + 2] = lz;
        }

        f32x2 lx2; lx2.x = lx; lx2.y = lx;
        f32x2 ly2; ly2.x = ly; ly2.y = ly;
        f32x2 lz2; lz2.x = lz; lz2.y = lz;

        // max-only scan (no argmax tracking); contract off => exact
#pragma unroll
        for (int j = 0; j < 8; ++j) {
            f32x2 dx = X[j] - lx2;
            f32x2 dy = Y[j] - ly2;
            f32x2 dz = Z[j] - lz2;
            f32x2 s  = (dx * dx + dy * dy) + dz * dz;
            D[j].x = fminf(D[j].x, s.x);
            D[j].y = fminf(D[j].y, s.y);
        }
        f32x2 m0 = pkmax(pkmax(D[0], D[1]), pkmax(D[2], D[3]));
        f32x2 m1 = pkmax(pkmax(D[4], D[5]), pkmax(D[6], D[7]));
        f32x2 mm = pkmax(m0, m1);
        float bv = fmaxf(mm.x, mm.y);

        // local first-argmax recovery (overlaps DPP chain; fmax is bit-exact
        // so at least one equality holds on every lane)
        int k0 = (D[0].x == bv) ? 0  : ((D[0].y == bv) ? 1  : 16);
        int k1 = (D[1].x == bv) ? 2  : ((D[1].y == bv) ? 3  : 16);
        int k2 = (D[2].x == bv) ? 4  : ((D[2].y == bv) ? 5  : 16);
        int k3 = (D[3].x == bv) ? 6  : ((D[3].y == bv) ? 7  : 16);
        int k4 = (D[4].x == bv) ? 8  : ((D[4].y == bv) ? 9  : 16);
        int k5 = (D[5].x == bv) ? 10 : ((D[5].y == bv) ? 11 : 16);
        int k6 = (D[6].x == bv) ? 12 : ((D[6].y == bv) ? 13 : 16);
        int k7 = (D[7].x == bv) ? 14 : ((D[7].y == bv) ? 15 : 16);
        k0 = min(k0, k4); k1 = min(k1, k5); k2 = min(k2, k6); k3 = min(k3, k7);
        k0 = min(k0, k2); k1 = min(k1, k3);
        int kmin = min(k0, k1);
        int p_cand = tid * 16 + kmin;

        // VALU-speed wave max-reduce: row_shr 1/2/4/8, row_bcast 15/31
        float r = bv;
        r = dppmax<0x111>(r);
        r = dppmax<0x112>(r);
        r = dppmax<0x114>(r);
        r = dppmax<0x118>(r);
        r = dppmax<0x142>(r);
        r = dppmax<0x143>(r);
        float wmax = __int_as_float(__builtin_amdgcn_readlane(__float_as_int(r), 63));

        // first-occurrence winner within wave (lane order == index order)
        unsigned long long msk = __ballot(bv == wmax);
        int wl = __ffsll((long long)msk) - 1;
        int pwin_wave = __builtin_amdgcn_readlane(p_cand, wl);   // uniform

        const int p_ = t & 1;
        if (lane == 0) {
            f32x2 sv; sv.x = wmax; sv.y = __int_as_float(pwin_wave);
            slot[p_][wv] = sv;
        }
        __syncthreads();   // single barrier per iteration (double-buffered)

        // merge 4 slots (two b128 reads, 3 dependent selects)
        f32x2 s0 = slot[p_][0], s1 = slot[p_][1];
        f32x2 s2 = slot[p_][2], s3 = slot[p_][3];
        float cv = s0.x; int ci = __float_as_int(s0.y);
        {
            int i1 = __float_as_int(s1.y);
            bool bt = (s1.x > cv) || (s1.x == cv && i1 < ci);
            cv = bt ? s1.x : cv; ci = bt ? i1 : ci;
        }
        {
            int i2 = __float_as_int(s2.y);
            bool bt = (s2.x > cv) || (s2.x == cv && i2 < ci);
            cv = bt ? s2.x : cv; ci = bt ? i2 : ci;
        }
        {
            int i3 = __float_as_int(s3.y);
            bool bt = (s3.x > cv) || (s3.x == cv && i3 < ci);
            cv = bt ? s3.x : cv; ci = bt ? i3 : ci;
        }

        float4 cw = posL[ci];   // broadcast read, conflict-free
        last = ci; lx = cw.x; ly = cw.y; lz = cw.z;
    }
}

// ---------------------------------------------------------------------------
// Kernel 2: radius search + exact K-smallest selection. One wave per center.
// ---------------------------------------------------------------------------
__global__ __launch_bounds__(256) void radius_kernel(
    const float* __restrict__ pos,
    const float* __restrict__ pos_s_ws,
    int* __restrict__ nbr_ws, int* __restrict__ nvalid_ws)
{
    __shared__ float d2L[4][CAP];
    __shared__ int   idL[4][CAP];
    __shared__ int   cntL[4];

    const int wv = threadIdx.x >> 6, lane = threadIdx.x & 63;
    const int c = blockIdx.x * 4 + wv;
    const int b = c >> 10;
    const float RSQ = 0.0225f;

    if (lane == 0) cntL[wv] = 0;

    float cx = pos_s_ws[c * 3 + 0];
    float cy = pos_s_ws[c * 3 + 1];
    float cz = pos_s_ws[c * 3 + 2];
    const float* pb = pos + (size_t)b * NN * 3;

    for (int it = 0; it < NN / 64; ++it) {
        int p = it * 64 + lane;
        float dx = __fsub_rn(cx, pb[p * 3 + 0]);
        float dy = __fsub_rn(cy, pb[p * 3 + 1]);
        float dz = __fsub_rn(cz, pb[p * 3 + 2]);
        float d2 = __fadd_rn(__fadd_rn(__fmul_rn(dx, dx), __fmul_rn(dy, dy)),
                             __fmul_rn(dz, dz));
        if (d2 <= RSQ) {
            int slot = atomicAdd(&cntL[wv], 1);
            if (slot < CAP) { d2L[wv][slot] = d2; idL[wv][slot] = p; }
        }
    }
    int n = cntL[wv];
    if (n > CAP) n = CAP;

    if (n <= KNB) {
        if (lane == 0) nvalid_ws[c] = n;
        if (lane < n) nbr_ws[c * KNB + lane] = idL[wv][lane];
    } else {
        if (lane == 0) nvalid_ws[c] = KNB;
        for (int a = lane; a < n; a += 64) {
            float da = d2L[wv][a]; int ia = idL[wv][a];
            int r = 0;
            for (int jj = 0; jj < n; ++jj) {
                float dj = d2L[wv][jj]; int ij = idL[wv][jj];
                r += (dj < da || (dj == da && ij < ia)) ? 1 : 0;
            }
            if (r < KNB) nbr_ws[c * KNB + r] = ia;
        }
    }
}

// ---------------------------------------------------------------------------
// Kernel 3: message build (x_j ++ ppf) -> 68x68 MLP x2 -> masked max-agg ->
// 68x128 output matvec. Block = 2 centers (64 edges), weights in LDS.
// ---------------------------------------------------------------------------
__device__ __forceinline__ float angle3(float ax, float ay, float az,
                                        float bx, float by, float bz)
{
    float cx = ay * bz - az * by;
    float cy = az * bx - ax * bz;
    float cz = ax * by - ay * bx;
    float cn = sqrtf(cx * cx + cy * cy + cz * cz);
    float dt = ax * bx + ay * by + az * bz;
    return atan2f(cn, dt);
}

__device__ __forceinline__ void layer_pass(const float* __restrict__ inL,
                                           const float* __restrict__ Ws,
                                           const float* __restrict__ bs,
                                           float* __restrict__ outL, int t)
{
    const int e = t & 63, wvi = t >> 6;
    for (int jg = wvi; jg < 17; jg += 4) {
        float ax = bs[jg * 4 + 0];
        float ay = bs[jg * 4 + 1];
        float az = bs[jg * 4 + 2];
        float aw = bs[jg * 4 + 3];
#pragma unroll 4
        for (int i = 0; i < DIM; ++i) {
            float m = inL[e * 69 + i];
            const float4 w = *reinterpret_cast<const float4*>(Ws + i * DIM + jg * 4);
            ax = fmaf(m, w.x, ax);
            ay = fmaf(m, w.y, ay);
            az = fmaf(m, w.z, az);
            aw = fmaf(m, w.w, aw);
        }
        outL[e * 69 + jg * 4 + 0] = fmaxf(ax, 0.0f);
        outL[e * 69 + jg * 4 + 1] = fmaxf(ay, 0.0f);
        outL[e * 69 + jg * 4 + 2] = fmaxf(az, 0.0f);
        outL[e * 69 + jg * 4 + 3] = fmaxf(aw, 0.0f);
    }
}

__global__ __launch_bounds__(256) void mlp_kernel(
    const float* __restrict__ x, const float* __restrict__ pos,
    const float* __restrict__ norm,
    const float* __restrict__ W1, const float* __restrict__ b1,
    const float* __restrict__ W2, const float* __restrict__ b2,
    const float* __restrict__ W3, const float* __restrict__ b3,
    const int* __restrict__ idx_ws, const float* __restrict__ pos_s_ws,
    const int* __restrict__ nbr_ws, const int* __restrict__ nvalid_ws,
    float* __restrict__ out)
{
    __shared__ alignas(16) float W1s[DIM * DIM];
    __shared__ alignas(16) float W2s[DIM * DIM];
    __shared__ float b1s[DIM], b2s[DIM];
    __shared__ float msgL[64 * 69];   // msg, later reused as h2
    __shared__ float h1L[64 * 69];
    __shared__ float aggL[2 * DIM];
    __shared__ int   nvL[2], jLs[64];

    const int t = threadIdx.x;
    const int cg0 = blockIdx.x * 2;

    for (int u = t; u < DIM * DIM; u += 256) { W1s[u] = W1[u]; W2s[u] = W2[u]; }
    if (t < DIM) { b1s[t] = b1[t]; b2s[t] = b2[t]; }
    if (t < 2) nvL[t] = min(nvalid_ws[cg0 + t], KNB);
    __syncthreads();

    const int e = t & 63, fc = t >> 6;
    const int lc = e >> 5, slot = e & 31;
    const int c = cg0 + lc;
    const int b = c >> 10;

    if (fc == 0) {
        int nv = nvL[lc];
        jLs[e] = (slot < nv) ? nbr_ws[c * KNB + slot] : 0;
    }
    __syncthreads();

    const int j = jLs[e];
    // gather x_j (each thread: 16 features of its edge)
    {
        const float* xj = x + ((size_t)b * NN + j) * NIN + fc * 16;
#pragma unroll
        for (int r = 0; r < 4; ++r) {
            float4 v = *reinterpret_cast<const float4*>(xj + r * 4);
            msgL[e * 69 + fc * 16 + r * 4 + 0] = v.x;
            msgL[e * 69 + fc * 16 + r * 4 + 1] = v.y;
            msgL[e * 69 + fc * 16 + r * 4 + 2] = v.z;
            msgL[e * 69 + fc * 16 + r * 4 + 3] = v.w;
        }
    }
    // point-pair features (one thread per edge)
    if (fc == 0) {
        float pix = pos_s_ws[c * 3 + 0];
        float piy = pos_s_ws[c * 3 + 1];
        float piz = pos_s_ws[c * 3 + 2];
        int ic = idx_ws[c];
        const float* pj_ = pos  + ((size_t)b * NN + j) * 3;
        const float* nj_ = norm + ((size_t)b * NN + j) * 3;
        const float* ni_ = norm + ((size_t)b * NN + ic) * 3;
        float dx = pj_[0] - pix, dy = pj_[1] - piy, dz = pj_[2] - piz;
        float nix = ni_[0], niy = ni_[1], niz = ni_[2];
        float njx = nj_[0], njy = nj_[1], njz = nj_[2];
        msgL[e * 69 + 64] = sqrtf(dx * dx + dy * dy + dz * dz);
        msgL[e * 69 + 65] = angle3(nix, niy, niz, dx, dy, dz);
        msgL[e * 69 + 66] = angle3(njx, njy, njz, dx, dy, dz);
        msgL[e * 69 + 67] = angle3(nix, niy, niz, njx, njy, njz);
    }
    __syncthreads();

    layer_pass(msgL, W1s, b1s, h1L, t);
    __syncthreads();
    layer_pass(h1L, W2s, b2s, msgL, t);   // h2 -> msgL
    __syncthreads();

    // masked max aggregation over valid slots
    if (t < 2 * DIM) {
        int cc = t / DIM, jf = t % DIM;
        int nv = nvL[cc];
        float v = -INFINITY;
        for (int s = 0; s < nv; ++s)
            v = fmaxf(v, msgL[(cc * 32 + s) * 69 + jf]);
        aggL[cc * DIM + jf] = v;
    }
    __syncthreads();

    // out = relu(agg @ W3 + b3)
    {
        int cc = t >> 7, o = t & 127;
        int cgl = cg0 + cc;
        float acc = b3[o];
#pragma unroll 4
        for (int i = 0; i < DIM; ++i)
            acc = fmaf(aggL[cc * DIM + i], W3[i * NOUTF + o], acc);
        out[(size_t)cgl * NOUTF + o] = fmaxf(acc, 0.0f);
    }
}

// ---------------------------------------------------------------------------
extern "C" void kernel_launch(void* const* d_in, const int* in_sizes, int n_in,
                              void* d_out, int out_size, void* d_ws, size_t ws_size,
                              hipStream_t stream)
{
    const float* x    = (const float*)d_in[0];
    const float* pos  = (const float*)d_in[1];
    const float* norm = (const float*)d_in[2];
    // d_in[3] = batch (unused, implicit in layout)
    const float* W1 = (const float*)d_in[4];
    const float* b1 = (const float*)d_in[5];
    const float* W2 = (const float*)d_in[6];
    const float* b2 = (const float*)d_in[7];
    const float* W3 = (const float*)d_in[8];
    const float* b3 = (const float*)d_in[9];

    float* out       = (float*)d_out;                       // [B*M*128]
    float* out_pos_s = out + (size_t)BB * MM * NOUTF;       // [B*M*3]
    float* out_idx   = out_pos_s + (size_t)BB * MM * 3;     // [B*M]

    char* ws = (char*)d_ws;
    int*   idx_ws    = (int*)ws;                                    // B*M
    float* pos_s_ws  = (float*)(ws + 32768);                        // B*M*3
    int*   nbr_ws    = (int*)(ws + 131072);                         // B*M*K
    int*   nvalid_ws = (int*)(ws + 131072 + (size_t)BB * MM * KNB * 4);

    fps_kernel<<<dim3(BB), dim3(256), 0, stream>>>(pos, idx_ws, pos_s_ws,
                                                   out_pos_s, out_idx);
    radius_kernel<<<dim3((BB * MM) / 4), dim3(256), 0, stream>>>(pos, pos_s_ws,
                                                                 nbr_ws, nvalid_ws);
    mlp_kernel<<<dim3((BB * MM) / 2), dim3(256), 0, stream>>>(
        x, pos, norm, W1, b1, W2, b2, W3, b3,
        idx_ws, pos_s_ws, nbr_ws, nvalid_ws, out);
}

// Round 7
// 1012.688 us; speedup vs baseline: 2.4620x; 1.0516x over previous
//
#include <hip/hip_runtime.h>
#include <hip/hip_bf16.h>
#include <math.h>

#define BB 8
#define NN 4096
#define NIN 64
#define NOUTF 128
#define KNB 32
#define MM 1024
#define DIM 68
#define CAP 320

typedef float f32x2 __attribute__((ext_vector_type(2)));

// Forced VOP3P packed f32 ops (compiler wasn't emitting these from vector IR).
// v_pk_add_f32 / v_pk_mul_f32: 64-bit register-pair operands, 2 IEEE f32 lanes.
__device__ __forceinline__ f32x2 pk_add(f32x2 a, f32x2 b)
{
    f32x2 d;
    asm("v_pk_add_f32 %0, %1, %2" : "=v"(d) : "v"(a), "v"(b));
    return d;
}
__device__ __forceinline__ f32x2 pk_mul(f32x2 a, f32x2 b)
{
    f32x2 d;
    asm("v_pk_mul_f32 %0, %1, %2" : "=v"(d) : "v"(a), "v"(b));
    return d;
}

__device__ __forceinline__ f32x2 pkmax(f32x2 a, f32x2 b)
{
    f32x2 r; r.x = fmaxf(a.x, b.x); r.y = fmaxf(a.y, b.y); return r;
}

// DPP max-reduce step: v = max(v, lanes-moved-v). CTRL compile-time.
template <int CTRL>
__device__ __forceinline__ float dppmax(float v)
{
    int m = __builtin_amdgcn_update_dpp(__float_as_int(v), __float_as_int(v),
                                        CTRL, 0xF, 0xF, false);
    return fmaxf(v, __int_as_float(m));
}

// ---------------------------------------------------------------------------
// Kernel 1: farthest point sampling. One block (4 waves) per batch.
// Exact-match constraints: no FMA contraction, (dx*dx+dy*dy)+dz*dz order,
// argmax = first occurrence (max value, then min global index).
// p = tid*16 + k mapping (lane/wave order == index order). Hot loop:
// packed-scan -> pkmax tree -> [DPP wave max || equality argmax recovery]
// -> ballot first-lane -> per-wave {val,idx} slot -> 1 barrier -> 3-select
// merge -> winner coords via broadcast ds_read_b128 from posL.
// ---------------------------------------------------------------------------
__global__ __launch_bounds__(256) void fps_kernel(
    const float* __restrict__ pos,
    int* __restrict__ idx_ws,
    float* __restrict__ out_pos_s, float* __restrict__ out_idx)
{
#pragma clang fp contract(off)
    __shared__ float4 posL[NN];        // 64 KiB coords for winner broadcast
    __shared__ f32x2  slot[2][4];      // {val, idx-as-bits} per wave, dbuf

    const int b    = blockIdx.x;
    const int tid  = threadIdx.x;
    const int wv   = tid >> 6;
    const int lane = tid & 63;
    const float* pb = pos + (size_t)b * NN * 3;

    // 16 consecutive points per thread: p = tid*16 + k.
    // Packed pairs: X[j].x <-> k=2j, X[j].y <-> k=2j+1.
    f32x2 X[8], Y[8], Z[8], D[8];
#pragma unroll
    for (int j = 0; j < 8; ++j) {
        int pA = tid * 16 + 2 * j;
        X[j].x = pb[pA * 3 + 0]; X[j].y = pb[pA * 3 + 3];
        Y[j].x = pb[pA * 3 + 1]; Y[j].y = pb[pA * 3 + 4];
        Z[j].x = pb[pA * 3 + 2]; Z[j].y = pb[pA * 3 + 5];
        D[j].x = INFINITY;       D[j].y = INFINITY;
    }
    // coalesced posL init: consecutive threads -> consecutive float4
#pragma unroll
    for (int j = 0; j < 16; ++j) {
        int p2 = tid + 256 * j;
        posL[p2] = make_float4(pb[p2 * 3 + 0], pb[p2 * 3 + 1],
                               pb[p2 * 3 + 2], 0.0f);
    }
    __syncthreads();

    int   last = 0;
    float lx = pb[0], ly = pb[1], lz = pb[2];

#pragma unroll 2
    for (int t = 0; t < MM; ++t) {
        // emit current sample (stores feed nothing; off critical path)
        if (tid == 0) {
            int base = b * MM + t;
            idx_ws[base]  = last;
            out_idx[base] = (float)last;
            out_pos_s[base * 3 + 0] = lx;
            out_pos_s[base * 3 + 1] = ly;
            out_pos_s[base * 3 + 2] = lz;
        }

        // negated center: X + (-lx) == X - lx bitwise (IEEE)
        float nx = -lx, ny = -ly, nz = -lz;
        f32x2 nx2; nx2.x = nx; nx2.y = nx;
        f32x2 ny2; ny2.x = ny; ny2.y = ny;
        f32x2 nz2; nz2.x = nz; nz2.y = nz;

        // packed scan: 8 pk-ops + 2 scalar mins per point-pair
#pragma unroll
        for (int j = 0; j < 8; ++j) {
            f32x2 dx = pk_add(X[j], nx2);
            f32x2 dy = pk_add(Y[j], ny2);
            f32x2 dz = pk_add(Z[j], nz2);
            f32x2 xx = pk_mul(dx, dx);
            f32x2 yy = pk_mul(dy, dy);
            f32x2 zz = pk_mul(dz, dz);
            f32x2 s  = pk_add(pk_add(xx, yy), zz);   // (x²+y²)+z² order
            D[j].x = fminf(D[j].x, s.x);
            D[j].y = fminf(D[j].y, s.y);
        }
        f32x2 m0 = pkmax(pkmax(D[0], D[1]), pkmax(D[2], D[3]));
        f32x2 m1 = pkmax(pkmax(D[4], D[5]), pkmax(D[6], D[7]));
        f32x2 mm = pkmax(m0, m1);
        float bv = fmaxf(mm.x, mm.y);

        // local first-argmax recovery (overlaps DPP chain; fmax selection is
        // bit-exact so at least one equality holds on every lane)
        int k0 = (D[0].x == bv) ? 0  : ((D[0].y == bv) ? 1  : 16);
        int k1 = (D[1].x == bv) ? 2  : ((D[1].y == bv) ? 3  : 16);
        int k2 = (D[2].x == bv) ? 4  : ((D[2].y == bv) ? 5  : 16);
        int k3 = (D[3].x == bv) ? 6  : ((D[3].y == bv) ? 7  : 16);
        int k4 = (D[4].x == bv) ? 8  : ((D[4].y == bv) ? 9  : 16);
        int k5 = (D[5].x == bv) ? 10 : ((D[5].y == bv) ? 11 : 16);
        int k6 = (D[6].x == bv) ? 12 : ((D[6].y == bv) ? 13 : 16);
        int k7 = (D[7].x == bv) ? 14 : ((D[7].y == bv) ? 15 : 16);
        k0 = min(k0, k4); k1 = min(k1, k5); k2 = min(k2, k6); k3 = min(k3, k7);
        k0 = min(k0, k2); k1 = min(k1, k3);
        int kmin = min(k0, k1);
        int p_cand = tid * 16 + kmin;

        // VALU-speed wave max-reduce: row_shr 1/2/4/8, row_bcast 15/31
        float r = bv;
        r = dppmax<0x111>(r);
        r = dppmax<0x112>(r);
        r = dppmax<0x114>(r);
        r = dppmax<0x118>(r);
        r = dppmax<0x142>(r);
        r = dppmax<0x143>(r);
        float wmax = __int_as_float(__builtin_amdgcn_readlane(__float_as_int(r), 63));

        // first-occurrence winner within wave (lane order == index order)
        unsigned long long msk = __ballot(bv == wmax);
        int wl = __ffsll((long long)msk) - 1;
        int pwin_wave = __builtin_amdgcn_readlane(p_cand, wl);   // uniform

        const int p_ = t & 1;
        if (lane == 0) {
            f32x2 sv; sv.x = wmax; sv.y = __int_as_float(pwin_wave);
            slot[p_][wv] = sv;
        }
        __syncthreads();   // single barrier per iteration (double-buffered)

        // merge 4 slots (two b128 reads, 3 dependent selects)
        f32x2 s0 = slot[p_][0], s1 = slot[p_][1];
        f32x2 s2 = slot[p_][2], s3 = slot[p_][3];
        float cv = s0.x; int ci = __float_as_int(s0.y);
        {
            int i1 = __float_as_int(s1.y);
            bool bt = (s1.x > cv) || (s1.x == cv && i1 < ci);
            cv = bt ? s1.x : cv; ci = bt ? i1 : ci;
        }
        {
            int i2 = __float_as_int(s2.y);
            bool bt = (s2.x > cv) || (s2.x == cv && i2 < ci);
            cv = bt ? s2.x : cv; ci = bt ? i2 : ci;
        }
        {
            int i3 = __float_as_int(s3.y);
            bool bt = (s3.x > cv) || (s3.x == cv && i3 < ci);
            cv = bt ? s3.x : cv; ci = bt ? i3 : ci;
        }

        float4 cw = posL[ci];   // broadcast read, conflict-free
        last = ci; lx = cw.x; ly = cw.y; lz = cw.z;
    }
}

// ---------------------------------------------------------------------------
// Kernel 2: radius search + exact K-smallest selection. One wave per center.
// pos_s now read from out_pos_s (fps writes it once, up front).
// ---------------------------------------------------------------------------
__global__ __launch_bounds__(256) void radius_kernel(
    const float* __restrict__ pos,
    const float* __restrict__ pos_s,
    int* __restrict__ nbr_ws, int* __restrict__ nvalid_ws)
{
    __shared__ float d2L[4][CAP];
    __shared__ int   idL[4][CAP];
    __shared__ int   cntL[4];

    const int wv = threadIdx.x >> 6, lane = threadIdx.x & 63;
    const int c = blockIdx.x * 4 + wv;
    const int b = c >> 10;
    const float RSQ = 0.0225f;

    if (lane == 0) cntL[wv] = 0;

    float cx = pos_s[c * 3 + 0];
    float cy = pos_s[c * 3 + 1];
    float cz = pos_s[c * 3 + 2];
    const float* pb = pos + (size_t)b * NN * 3;

    for (int it = 0; it < NN / 64; ++it) {
        int p = it * 64 + lane;
        float dx = __fsub_rn(cx, pb[p * 3 + 0]);
        float dy = __fsub_rn(cy, pb[p * 3 + 1]);
        float dz = __fsub_rn(cz, pb[p * 3 + 2]);
        float d2 = __fadd_rn(__fadd_rn(__fmul_rn(dx, dx), __fmul_rn(dy, dy)),
                             __fmul_rn(dz, dz));
        if (d2 <= RSQ) {
            int slot = atomicAdd(&cntL[wv], 1);
            if (slot < CAP) { d2L[wv][slot] = d2; idL[wv][slot] = p; }
        }
    }
    int n = cntL[wv];
    if (n > CAP) n = CAP;

    if (n <= KNB) {
        if (lane == 0) nvalid_ws[c] = n;
        if (lane < n) nbr_ws[c * KNB + lane] = idL[wv][lane];
    } else {
        if (lane == 0) nvalid_ws[c] = KNB;
        for (int a = lane; a < n; a += 64) {
            float da = d2L[wv][a]; int ia = idL[wv][a];
            int r = 0;
            for (int jj = 0; jj < n; ++jj) {
                float dj = d2L[wv][jj]; int ij = idL[wv][jj];
                r += (dj < da || (dj == da && ij < ia)) ? 1 : 0;
            }
            if (r < KNB) nbr_ws[c * KNB + r] = ia;
        }
    }
}

// ---------------------------------------------------------------------------
// Kernel 3: message build (x_j ++ ppf) -> 68x68 MLP x2 -> masked max-agg ->
// 68x128 output matvec. Block = 2 centers (64 edges), weights in LDS.
// ---------------------------------------------------------------------------
__device__ __forceinline__ float angle3(float ax, float ay, float az,
                                        float bx, float by, float bz)
{
    float cx = ay * bz - az * by;
    float cy = az * bx - ax * bz;
    float cz = ax * by - ay * bx;
    float cn = sqrtf(cx * cx + cy * cy + cz * cz);
    float dt = ax * bx + ay * by + az * bz;
    return atan2f(cn, dt);
}

__device__ __forceinline__ void layer_pass(const float* __restrict__ inL,
                                           const float* __restrict__ Ws,
                                           const float* __restrict__ bs,
                                           float* __restrict__ outL, int t)
{
    const int e = t & 63, wvi = t >> 6;
    for (int jg = wvi; jg < 17; jg += 4) {
        float ax = bs[jg * 4 + 0];
        float ay = bs[jg * 4 + 1];
        float az = bs[jg * 4 + 2];
        float aw = bs[jg * 4 + 3];
#pragma unroll 4
        for (int i = 0; i < DIM; ++i) {
            float m = inL[e * 69 + i];
            const float4 w = *reinterpret_cast<const float4*>(Ws + i * DIM + jg * 4);
            ax = fmaf(m, w.x, ax);
            ay = fmaf(m, w.y, ay);
            az = fmaf(m, w.z, az);
            aw = fmaf(m, w.w, aw);
        }
        outL[e * 69 + jg * 4 + 0] = fmaxf(ax, 0.0f);
        outL[e * 69 + jg * 4 + 1] = fmaxf(ay, 0.0f);
        outL[e * 69 + jg * 4 + 2] = fmaxf(az, 0.0f);
        outL[e * 69 + jg * 4 + 3] = fmaxf(aw, 0.0f);
    }
}

__global__ __launch_bounds__(256) void mlp_kernel(
    const float* __restrict__ x, const float* __restrict__ pos,
    const float* __restrict__ norm,
    const float* __restrict__ W1, const float* __restrict__ b1,
    const float* __restrict__ W2, const float* __restrict__ b2,
    const float* __restrict__ W3, const float* __restrict__ b3,
    const int* __restrict__ idx_ws, const float* __restrict__ pos_s,
    const int* __restrict__ nbr_ws, const int* __restrict__ nvalid_ws,
    float* __restrict__ out)
{
    __shared__ alignas(16) float W1s[DIM * DIM];
    __shared__ alignas(16) float W2s[DIM * DIM];
    __shared__ float b1s[DIM], b2s[DIM];
    __shared__ float msgL[64 * 69];   // msg, later reused as h2
    __shared__ float h1L[64 * 69];
    __shared__ float aggL[2 * DIM];
    __shared__ int   nvL[2], jLs[64];

    const int t = threadIdx.x;
    const int cg0 = blockIdx.x * 2;

    for (int u = t; u < DIM * DIM; u += 256) { W1s[u] = W1[u]; W2s[u] = W2[u]; }
    if (t < DIM) { b1s[t] = b1[t]; b2s[t] = b2[t]; }
    if (t < 2) nvL[t] = min(nvalid_ws[cg0 + t], KNB);
    __syncthreads();

    const int e = t & 63, fc = t >> 6;
    const int lc = e >> 5, slot = e & 31;
    const int c = cg0 + lc;
    const int b = c >> 10;

    if (fc == 0) {
        int nv = nvL[lc];
        jLs[e] = (slot < nv) ? nbr_ws[c * KNB + slot] : 0;
    }
    __syncthreads();

    const int j = jLs[e];
    // gather x_j (each thread: 16 features of its edge)
    {
        const float* xj = x + ((size_t)b * NN + j) * NIN + fc * 16;
#pragma unroll
        for (int r = 0; r < 4; ++r) {
            float4 v = *reinterpret_cast<const float4*>(xj + r * 4);
            msgL[e * 69 + fc * 16 + r * 4 + 0] = v.x;
            msgL[e * 69 + fc * 16 + r * 4 + 1] = v.y;
            msgL[e * 69 + fc * 16 + r * 4 + 2] = v.z;
            msgL[e * 69 + fc * 16 + r * 4 + 3] = v.w;
        }
    }
    // point-pair features (one thread per edge)
    if (fc == 0) {
        float pix = pos_s[c * 3 + 0];
        float piy = pos_s[c * 3 + 1];
        float piz = pos_s[c * 3 + 2];
        int ic = idx_ws[c];
        const float* pj_ = pos  + ((size_t)b * NN + j) * 3;
        const float* nj_ = norm + ((size_t)b * NN + j) * 3;
        const float* ni_ = norm + ((size_t)b * NN + ic) * 3;
        float dx = pj_[0] - pix, dy = pj_[1] - piy, dz = pj_[2] - piz;
        float nix = ni_[0], niy = ni_[1], niz = ni_[2];
        float njx = nj_[0], njy = nj_[1], njz = nj_[2];
        msgL[e * 69 + 64] = sqrtf(dx * dx + dy * dy + dz * dz);
        msgL[e * 69 + 65] = angle3(nix, niy, niz, dx, dy, dz);
        msgL[e * 69 + 66] = angle3(njx, njy, njz, dx, dy, dz);
        msgL[e * 69 + 67] = angle3(nix, niy, niz, njx, njy, njz);
    }
    __syncthreads();

    layer_pass(msgL, W1s, b1s, h1L, t);
    __syncthreads();
    layer_pass(h1L, W2s, b2s, msgL, t);   // h2 -> msgL
    __syncthreads();

    // masked max aggregation over valid slots
    if (t < 2 * DIM) {
        int cc = t / DIM, jf = t % DIM;
        int nv = nvL[cc];
        float v = -INFINITY;
        for (int s = 0; s < nv; ++s)
            v = fmaxf(v, msgL[(cc * 32 + s) * 69 + jf]);
        aggL[cc * DIM + jf] = v;
    }
    __syncthreads();

    // out = relu(agg @ W3 + b3)
    {
        int cc = t >> 7, o = t & 127;
        int cgl = cg0 + cc;
        float acc = b3[o];
#pragma unroll 4
        for (int i = 0; i < DIM; ++i)
            acc = fmaf(aggL[cc * DIM + i], W3[i * NOUTF + o], acc);
        out[(size_t)cgl * NOUTF + o] = fmaxf(acc, 0.0f);
    }
}

// ---------------------------------------------------------------------------
extern "C" void kernel_launch(void* const* d_in, const int* in_sizes, int n_in,
                              void* d_out, int out_size, void* d_ws, size_t ws_size,
                              hipStream_t stream)
{
    const float* x    = (const float*)d_in[0];
    const float* pos  = (const float*)d_in[1];
    const float* norm = (const float*)d_in[2];
    // d_in[3] = batch (unused, implicit in layout)
    const float* W1 = (const float*)d_in[4];
    const float* b1 = (const float*)d_in[5];
    const float* W2 = (const float*)d_in[6];
    const float* b2 = (const float*)d_in[7];
    const float* W3 = (const float*)d_in[8];
    const float* b3 = (const float*)d_in[9];

    float* out       = (float*)d_out;                       // [B*M*128]
    float* out_pos_s = out + (size_t)BB * MM * NOUTF;       // [B*M*3]
    float* out_idx   = out_pos_s + (size_t)BB * MM * 3;     // [B*M]

    char* ws = (char*)d_ws;
    int*   idx_ws    = (int*)ws;                                    // B*M
    int*   nbr_ws    = (int*)(ws + 131072);                         // B*M*K
    int*   nvalid_ws = (int*)(ws + 131072 + (size_t)BB * MM * KNB * 4);

    fps_kernel<<<dim3(BB), dim3(256), 0, stream>>>(pos, idx_ws,
                                                   out_pos_s, out_idx);
    radius_kernel<<<dim3((BB * MM) / 4), dim3(256), 0, stream>>>(pos, out_pos_s,
                                                                 nbr_ws, nvalid_ws);
    mlp_kernel<<<dim3((BB * MM) / 2), dim3(256), 0, stream>>>(
        x, pos, norm, W1, b1, W2, b2, W3, b3,
        idx_ws, out_pos_s, nbr_ws, nvalid_ws, out);
}